// Round 1
// baseline (1023.068 us; speedup 1.0000x reference)
//
#include <hip/hip_runtime.h>

#define NUM_GRAPHS 64

__global__ __launch_bounds__(256) void harmonic_edges_kernel(
    const float* __restrict__ pos,     // [N,3]
    const int*   __restrict__ ei,      // [2,E]
    const int*   __restrict__ batch,   // [N]
    float*       __restrict__ energy,  // [64]
    float*       __restrict__ forces,  // [N,3]
    int E)
{
    __shared__ float ebins[NUM_GRAPHS];
    const int t = threadIdx.x;
    if (t < NUM_GRAPHS) ebins[t] = 0.0f;
    __syncthreads();

    const int stride = gridDim.x * blockDim.x;
    for (int e = blockIdx.x * blockDim.x + t; e < E; e += stride) {
        const int i = ei[e];
        const int j = ei[E + e];

        const float xi = pos[3 * i + 0];
        const float yi = pos[3 * i + 1];
        const float zi = pos[3 * i + 2];
        const float xj = pos[3 * j + 0];
        const float yj = pos[3 * j + 1];
        const float zj = pos[3 * j + 2];

        const float dx = xi - xj;
        const float dy = yi - yj;
        const float dz = zi - zj;

        const float d     = sqrtf(dx * dx + dy * dy + dz * dz);
        const float delta = d - 1.0f;                 // R0 = 1
        const float ee    = 0.5f * delta * delta;     // K = 1

        atomicAdd(&ebins[batch[i]], ee);

        const float s  = delta / (d + 1e-20f);        // K*delta/(d+EPS)
        const float fx = s * dx;
        const float fy = s * dy;
        const float fz = s * dz;

        atomicAdd(&forces[3 * i + 0], -fx);
        atomicAdd(&forces[3 * i + 1], -fy);
        atomicAdd(&forces[3 * i + 2], -fz);
        atomicAdd(&forces[3 * j + 0],  fx);
        atomicAdd(&forces[3 * j + 1],  fy);
        atomicAdd(&forces[3 * j + 2],  fz);
    }

    __syncthreads();
    if (t < NUM_GRAPHS) atomicAdd(&energy[t], ebins[t]);
}

extern "C" void kernel_launch(void* const* d_in, const int* in_sizes, int n_in,
                              void* d_out, int out_size, void* d_ws, size_t ws_size,
                              hipStream_t stream) {
    const float* pos   = (const float*)d_in[0];
    const int*   ei    = (const int*)d_in[1];
    const int*   batch = (const int*)d_in[2];

    const int E = in_sizes[1] / 2;   // edge_index is [2, E]

    float* energy = (float*)d_out;            // first 64 floats
    float* forces = (float*)d_out + NUM_GRAPHS;

    // Output buffer is poisoned 0xAA before every launch — zero it (energy +
    // forces are accumulated via atomics).
    hipMemsetAsync(d_out, 0, (size_t)out_size * sizeof(float), stream);

    const int block = 256;
    const int grid  = 2048;   // grid-stride: ~6 edges/thread, 131K energy atomics total
    harmonic_edges_kernel<<<grid, block, 0, stream>>>(pos, ei, batch, energy, forces, E);
}

// Round 2
// 704.861 us; speedup vs baseline: 1.4514x; 1.4514x over previous
//
#include <hip/hip_runtime.h>

#define NUM_GRAPHS 64
#define CHUNK_NODES 4096
#define CHUNK_FLOATS (CHUNK_NODES * 3)   // 12288 floats = 48 KB LDS
#define BLOCK 256
#define MAX_SLICES 32

// Pass A: each block owns (chunk, slice). It scans its slice of the edge
// list, accumulates force contributions for nodes inside its chunk into an
// LDS-private accumulator (LDS atomics only), and accumulates edge energy
// (counted once per edge: by the chunk owning endpoint i). Partial force
// sums go to d_ws coalesced; energy bins go to d_out[0..63] via 64 global
// atomics per block.
__global__ __launch_bounds__(BLOCK) void edge_scan_kernel(
    const float* __restrict__ pos,     // [N,3]
    const int*   __restrict__ ei,      // [2,E]
    const int*   __restrict__ batch,   // [N]
    float*       __restrict__ energy,  // d_out[0..63], pre-zeroed
    float*       __restrict__ partials,// ws: [slices*chunks][CHUNK_FLOATS]
    int E, int chunks, int per_slice)
{
    __shared__ float facc[CHUNK_FLOATS];
    __shared__ float ebins[NUM_GRAPHS];

    const int t = threadIdx.x;
    #pragma unroll 4
    for (int idx = t; idx < CHUNK_FLOATS; idx += BLOCK) facc[idx] = 0.f;
    if (t < NUM_GRAPHS) ebins[t] = 0.f;
    __syncthreads();

    const int chunk = blockIdx.x % chunks;
    const int lo = chunk * CHUNK_NODES;
    const int hi = lo + CHUNK_NODES;   // node indices are < N, so hi>N is harmless

    const int slice   = blockIdx.x / chunks;
    const int e_begin = slice * per_slice;
    const int e_end   = min(E, e_begin + per_slice);

    for (int e = e_begin + t; e < e_end; e += BLOCK) {
        const int i = ei[e];
        const int j = ei[E + e];
        const bool ini = (i >= lo) & (i < hi);
        const bool inj = (j >= lo) & (j < hi);
        if (!(ini | inj)) continue;    // ~92% of visits skip here

        const float xi = pos[3*i+0], yi = pos[3*i+1], zi = pos[3*i+2];
        const float xj = pos[3*j+0], yj = pos[3*j+1], zj = pos[3*j+2];
        const float dx = xi - xj, dy = yi - yj, dz = zi - zj;

        const float d     = sqrtf(dx*dx + dy*dy + dz*dz);
        const float delta = d - 1.0f;                 // R0 = 1
        const float s     = delta / (d + 1e-20f);     // K = 1
        const float fx = s*dx, fy = s*dy, fz = s*dz;

        if (ini) {
            atomicAdd(&ebins[batch[i]], 0.5f * delta * delta);
            const int l = (i - lo) * 3;
            atomicAdd(&facc[l+0], -fx);
            atomicAdd(&facc[l+1], -fy);
            atomicAdd(&facc[l+2], -fz);
        }
        if (inj) {
            const int l = (j - lo) * 3;
            atomicAdd(&facc[l+0], fx);
            atomicAdd(&facc[l+1], fy);
            atomicAdd(&facc[l+2], fz);
        }
    }

    __syncthreads();
    float* dst = partials + (size_t)blockIdx.x * CHUNK_FLOATS;
    #pragma unroll 4
    for (int idx = t; idx < CHUNK_FLOATS; idx += BLOCK) dst[idx] = facc[idx];
    if (t < NUM_GRAPHS) atomicAdd(&energy[t], ebins[t]);
}

// Pass B: forces[f] = sum over slices of the chunk-partial holding f.
// Coalesced reads (consecutive f -> consecutive addresses within a partial).
__global__ __launch_bounds__(BLOCK) void reduce_kernel(
    const float* __restrict__ partials,
    float*       __restrict__ forces,
    int total_floats, int chunks, int slices)
{
    const int f = blockIdx.x * BLOCK + threadIdx.x;
    if (f >= total_floats) return;
    const int chunk = f / CHUNK_FLOATS;
    const int rem   = f - chunk * CHUNK_FLOATS;
    float sum = 0.f;
    for (int s = 0; s < slices; ++s)
        sum += partials[(size_t)(s * chunks + chunk) * CHUNK_FLOATS + rem];
    forces[f] = sum;
}

extern "C" void kernel_launch(void* const* d_in, const int* in_sizes, int n_in,
                              void* d_out, int out_size, void* d_ws, size_t ws_size,
                              hipStream_t stream) {
    const float* pos   = (const float*)d_in[0];
    const int*   ei    = (const int*)d_in[1];
    const int*   batch = (const int*)d_in[2];

    const int E = in_sizes[1] / 2;     // edge_index is [2, E]
    const int N = in_sizes[0] / 3;     // pos is [N, 3]

    float* energy = (float*)d_out;            // first 64 floats
    float* forces = (float*)d_out + NUM_GRAPHS;

    const int chunks = (N + CHUNK_NODES - 1) / CHUNK_NODES;   // 25 for N=100000

    // slices bounded by workspace: one slice-set = chunks * 48 KB.
    const size_t slice_bytes = (size_t)chunks * CHUNK_FLOATS * sizeof(float);
    int slices = (int)(ws_size / slice_bytes);
    if (slices > MAX_SLICES) slices = MAX_SLICES;
    if (slices < 1) slices = 1;
    const int per_slice = (E + slices - 1) / slices;

    // Only energy is accumulated via atomics into d_out; forces are fully
    // overwritten by reduce_kernel.
    hipMemsetAsync(d_out, 0, NUM_GRAPHS * sizeof(float), stream);

    edge_scan_kernel<<<chunks * slices, BLOCK, 0, stream>>>(
        pos, ei, batch, energy, (float*)d_ws, E, chunks, per_slice);

    const int total_floats = 3 * N;
    reduce_kernel<<<(total_floats + BLOCK - 1) / BLOCK, BLOCK, 0, stream>>>(
        (const float*)d_ws, forces, total_floats, chunks, slices);
}

// Round 3
// 298.582 us; speedup vs baseline: 3.4264x; 2.3607x over previous
//
#include <hip/hip_runtime.h>

#define NUM_GRAPHS 64
#define CHUNK_NODES 4096
#define CHUNK_FLOATS (CHUNK_NODES * 3)   // 12288 floats = 48 KB LDS
#define BLOCK 256
#define WAVES (BLOCK / 64)
#define QCAP 320                          // per-wave ring entries; 48K+5K+256B = 54528 B -> 3 blocks/CU
#define MAX_SLICES 32

// Pass A: block owns (chunk, slice). Scan slice edges with int4 loads; push
// survivors (edge id + ini/inj flags) into a wave-private LDS ring via
// ballot-prefix; drain in dense 64-wide batches into the LDS force
// accumulator. Energy counted once per edge (by chunk owning endpoint i).
__global__ __launch_bounds__(BLOCK) void edge_scan_kernel(
    const float* __restrict__ pos,      // [N,3]
    const int*   __restrict__ ei,       // [2,E]
    const int*   __restrict__ batch,    // [N]
    float*       __restrict__ energy,   // d_out[0..63], pre-zeroed
    float*       __restrict__ partials, // ws: [slices*chunks][CHUNK_FLOATS]
    int E, int chunks, int slices, int per_slice)
{
    __shared__ float facc[CHUNK_FLOATS];
    __shared__ float ebins[NUM_GRAPHS];
    __shared__ unsigned int q[WAVES][QCAP];

    const int t    = threadIdx.x;
    const int lane = t & 63;
    const int w    = t >> 6;

    for (int idx = 4 * t; idx < CHUNK_FLOATS; idx += 4 * BLOCK) {
        float4 z = {0.f, 0.f, 0.f, 0.f};
        *(float4*)&facc[idx] = z;
    }
    if (t < NUM_GRAPHS) ebins[t] = 0.f;
    __syncthreads();

    // XCD swizzle: same-slice blocks cluster on one XCD (blockIdx % 8
    // heuristic) so the slice's edge data is L2-resident per XCD.
    int chunk, slice;
    const int b = blockIdx.x;
    if ((slices & 7) == 0) {
        const int g = b & 7;
        const int k = b >> 3;
        slice = g + 8 * (k / chunks);
        chunk = k % chunks;
    } else {
        chunk = b % chunks;
        slice = b / chunks;
    }

    const int lo      = chunk * CHUNK_NODES;
    const int e_begin = slice * per_slice;
    const int e_end   = min(E, e_begin + per_slice);

    unsigned int head = 0, tail = 0, cnt = 0;   // wave-uniform scalars

    auto drain = [&](unsigned int k) {          // k <= 64
        __builtin_amdgcn_wave_barrier();        // order queue writes vs reads
        if (lane < (int)k) {
            unsigned int idx = head + lane; if (idx >= QCAP) idx -= QCAP;
            const unsigned int entry = q[w][idx];
            const int e   = entry & 0x3FFFFFFF;
            const int ini = (entry >> 30) & 1;
            const int inj = (int)(entry >> 31);
            const int iv = ei[e];
            const int jv = ei[E + e];
            const float xi = pos[3*iv], yi = pos[3*iv+1], zi = pos[3*iv+2];
            const float xj = pos[3*jv], yj = pos[3*jv+1], zj = pos[3*jv+2];
            const float dx = xi - xj, dy = yi - yj, dz = zi - zj;
            const float d     = sqrtf(dx*dx + dy*dy + dz*dz);
            const float delta = d - 1.0f;                 // R0 = 1
            const float s     = delta / (d + 1e-20f);     // K = 1
            const float fx = s*dx, fy = s*dy, fz = s*dz;
            if (ini) {
                atomicAdd(&ebins[batch[iv]], 0.5f * delta * delta);
                const int l = (iv - lo) * 3;
                atomicAdd(&facc[l+0], -fx);
                atomicAdd(&facc[l+1], -fy);
                atomicAdd(&facc[l+2], -fz);
            }
            if (inj) {
                const int l = (jv - lo) * 3;
                atomicAdd(&facc[l+0], fx);
                atomicAdd(&facc[l+1], fy);
                atomicAdd(&facc[l+2], fz);
            }
        }
        head += k; if (head >= QCAP) head -= QCAP;
        cnt  -= k;
    };

    // Wave-uniform trip count: loop bound on wave base, per-lane bounds
    // handled by predicates (keeps ballot/queue scalars uniform).
    for (int base = e_begin + 256 * w; base < e_end; base += 4 * BLOCK) {
        const int e0 = base + 4 * lane;
        int4 ii, jj;
        if (e0 + 3 < e_end) {
            ii = *(const int4*)(ei + e0);
            jj = *(const int4*)(ei + E + e0);
        } else {
            const int sent = 0x7fffffff;   // fails the in-chunk test
            ii.x = (e0     < e_end) ? ei[e0]       : sent;
            ii.y = (e0 + 1 < e_end) ? ei[e0 + 1]   : sent;
            ii.z = (e0 + 2 < e_end) ? ei[e0 + 2]   : sent;
            ii.w = (e0 + 3 < e_end) ? ei[e0 + 3]   : sent;
            jj.x = (e0     < e_end) ? ei[E+e0]     : sent;
            jj.y = (e0 + 1 < e_end) ? ei[E+e0 + 1] : sent;
            jj.z = (e0 + 2 < e_end) ? ei[E+e0 + 2] : sent;
            jj.w = (e0 + 3 < e_end) ? ei[E+e0 + 3] : sent;
        }
        #pragma unroll
        for (int s = 0; s < 4; ++s) {
            const int iv = (s == 0) ? ii.x : (s == 1) ? ii.y : (s == 2) ? ii.z : ii.w;
            const int jv = (s == 0) ? jj.x : (s == 1) ? jj.y : (s == 2) ? jj.z : jj.w;
            const unsigned int ini = (unsigned int)(iv - lo) < CHUNK_NODES;
            const unsigned int inj = (unsigned int)(jv - lo) < CHUNK_NODES;
            const bool p = (ini | inj) != 0;
            const unsigned long long m = __ballot(p);
            if (p) {
                const unsigned int off = __popcll(m & ((1ull << lane) - 1ull));
                unsigned int qp = tail + off; if (qp >= QCAP) qp -= QCAP;
                q[w][qp] = (unsigned int)(e0 + s) | (ini << 30) | (inj << 31);
            }
            const unsigned int c = (unsigned int)__popcll(m);
            tail += c; if (tail >= QCAP) tail -= QCAP;
            cnt  += c;
        }
        while (cnt >= 64) drain(64);
    }
    while (cnt > 0) drain(cnt < 64 ? cnt : 64);

    __syncthreads();
    float* dst = partials + (size_t)(slice * chunks + chunk) * CHUNK_FLOATS;
    for (int idx = 4 * t; idx < CHUNK_FLOATS; idx += 4 * BLOCK)
        *(float4*)(dst + idx) = *(const float4*)&facc[idx];
    if (t < NUM_GRAPHS) atomicAdd(&energy[t], ebins[t]);
}

// Pass B: forces[f] = sum over slices of the chunk-partial holding f.
__global__ __launch_bounds__(BLOCK) void reduce_kernel(
    const float* __restrict__ partials,
    float*       __restrict__ forces,
    int total_floats, int chunks, int slices)
{
    const int f = blockIdx.x * BLOCK + threadIdx.x;
    if (f >= total_floats) return;
    const int chunk = f / CHUNK_FLOATS;
    const int rem   = f - chunk * CHUNK_FLOATS;
    float sum = 0.f;
    for (int s = 0; s < slices; ++s)
        sum += partials[(size_t)(s * chunks + chunk) * CHUNK_FLOATS + rem];
    forces[f] = sum;
}

extern "C" void kernel_launch(void* const* d_in, const int* in_sizes, int n_in,
                              void* d_out, int out_size, void* d_ws, size_t ws_size,
                              hipStream_t stream) {
    const float* pos   = (const float*)d_in[0];
    const int*   ei    = (const int*)d_in[1];
    const int*   batch = (const int*)d_in[2];

    const int E = in_sizes[1] / 2;     // edge_index is [2, E]
    const int N = in_sizes[0] / 3;     // pos is [N, 3]

    float* energy = (float*)d_out;            // first 64 floats
    float* forces = (float*)d_out + NUM_GRAPHS;

    const int chunks = (N + CHUNK_NODES - 1) / CHUNK_NODES;   // 25 for N=100000

    const size_t slice_bytes = (size_t)chunks * CHUNK_FLOATS * sizeof(float);
    int slices = (int)(ws_size / slice_bytes);
    if (slices > MAX_SLICES) slices = MAX_SLICES;   // 32: divisible by 8 for XCD swizzle
    if (slices < 1) slices = 1;
    // per_slice multiple of 1024 so every int4 scan load is in-bounds & aligned
    int per_slice = (E + slices - 1) / slices;
    per_slice = (per_slice + 1023) & ~1023;

    // Only energy accumulates via atomics into d_out; forces fully overwritten.
    hipMemsetAsync(d_out, 0, NUM_GRAPHS * sizeof(float), stream);

    edge_scan_kernel<<<chunks * slices, BLOCK, 0, stream>>>(
        pos, ei, batch, energy, (float*)d_ws, E, chunks, slices, per_slice);

    const int total_floats = 3 * N;
    reduce_kernel<<<(total_floats + BLOCK - 1) / BLOCK, BLOCK, 0, stream>>>(
        (const float*)d_ws, forces, total_floats, chunks, slices);
}

// Round 4
// 223.840 us; speedup vs baseline: 4.5705x; 1.3339x over previous
//
#include <hip/hip_runtime.h>

#define NUM_GRAPHS 64
#define CHUNK_NODES 10240
#define CHUNK_FLOATS (CHUNK_NODES * 3)   // 30720 floats = 120 KB LDS
#define BLOCK 1024
#define WAVES (BLOCK / 64)               // 16
#define QCAP 320                         // >= 63 + 4*64 worst-case growth
#define SLICES 24                        // divisible by 8 (XCD swizzle), grid = 240 <= 256

// Pass A: block owns (chunk, slice). Scan slice edges with int4 loads; push
// survivors (edge id + ini/inj flags) into a wave-private LDS ring via
// ballot-prefix; drain in dense 64-wide batches into the 120 KB LDS force
// accumulator. Energy counted once per edge (by chunk owning endpoint i).
// LDS total: 120K facc + 20K queues + 256B ebins = 143.6 KB -> 1 block/CU,
// 16 waves/CU (4/SIMD).
__global__ __launch_bounds__(BLOCK, 4) void edge_scan_kernel(
    const float* __restrict__ pos,      // [N,3]
    const int*   __restrict__ ei,       // [2,E]
    const int*   __restrict__ batch,    // [N]
    float*       __restrict__ energy,   // d_out[0..63], pre-zeroed
    float*       __restrict__ partials, // ws: [slices*chunks][CHUNK_FLOATS]
    int E, int chunks, int slices, int per_slice, int swizzle)
{
    __shared__ float facc[CHUNK_FLOATS];
    __shared__ float ebins[NUM_GRAPHS];
    __shared__ unsigned int q[WAVES][QCAP];

    const int t    = threadIdx.x;
    const int lane = t & 63;
    const int w    = t >> 6;

    for (int idx = 4 * t; idx < CHUNK_FLOATS; idx += 4 * BLOCK) {
        float4 z = {0.f, 0.f, 0.f, 0.f};
        *(float4*)&facc[idx] = z;
    }
    if (t < NUM_GRAPHS) ebins[t] = 0.f;
    __syncthreads();

    // XCD swizzle: blocks sharing a slice land on one XCD (b%8 heuristic),
    // so each slice's edge rows stay resident in that XCD's L2 across the
    // `chunks` re-reads.
    int chunk, slice;
    const int b = blockIdx.x;
    if (swizzle) {
        const int g = b & 7;          // XCD id heuristic
        const int k = b >> 3;
        slice = g + 8 * (k / chunks);
        chunk = k % chunks;
    } else {
        chunk = b % chunks;
        slice = b / chunks;
    }

    const int lo      = chunk * CHUNK_NODES;
    const int e_begin = slice * per_slice;
    const int e_end   = min(E, e_begin + per_slice);

    unsigned int head = 0, tail = 0, cnt = 0;   // wave-uniform scalars

    auto drain = [&](unsigned int k) {          // k <= 64
        __builtin_amdgcn_wave_barrier();        // order queue writes vs reads
        if (lane < (int)k) {
            unsigned int idx = head + lane; if (idx >= QCAP) idx -= QCAP;
            const unsigned int entry = q[w][idx];
            const int e   = entry & 0x3FFFFFFF;
            const int ini = (entry >> 30) & 1;
            const int inj = (int)(entry >> 31);
            const int iv = ei[e];
            const int jv = ei[E + e];
            const float xi = pos[3*iv], yi = pos[3*iv+1], zi = pos[3*iv+2];
            const float xj = pos[3*jv], yj = pos[3*jv+1], zj = pos[3*jv+2];
            const float dx = xi - xj, dy = yi - yj, dz = zi - zj;
            const float d     = sqrtf(dx*dx + dy*dy + dz*dz);
            const float delta = d - 1.0f;                 // R0 = 1
            const float s     = delta / (d + 1e-20f);     // K = 1
            const float fx = s*dx, fy = s*dy, fz = s*dz;
            if (ini) {
                atomicAdd(&ebins[batch[iv]], 0.5f * delta * delta);
                const int l = (iv - lo) * 3;
                atomicAdd(&facc[l+0], -fx);
                atomicAdd(&facc[l+1], -fy);
                atomicAdd(&facc[l+2], -fz);
            }
            if (inj) {
                const int l = (jv - lo) * 3;
                atomicAdd(&facc[l+0], fx);
                atomicAdd(&facc[l+1], fy);
                atomicAdd(&facc[l+2], fz);
            }
        }
        head += k; if (head >= QCAP) head -= QCAP;
        cnt  -= k;
    };

    // Wave-uniform trip count; per-lane tail handled by sentinel predicates.
    for (int base = e_begin + 256 * w; base < e_end; base += 4 * BLOCK) {
        const int e0 = base + 4 * lane;
        int4 ii, jj;
        if (e0 + 3 < e_end) {
            ii = *(const int4*)(ei + e0);
            jj = *(const int4*)(ei + E + e0);
        } else {
            const int sent = 0x7fffffff;   // fails the in-chunk test
            ii.x = (e0     < e_end) ? ei[e0]       : sent;
            ii.y = (e0 + 1 < e_end) ? ei[e0 + 1]   : sent;
            ii.z = (e0 + 2 < e_end) ? ei[e0 + 2]   : sent;
            ii.w = (e0 + 3 < e_end) ? ei[e0 + 3]   : sent;
            jj.x = (e0     < e_end) ? ei[E+e0]     : sent;
            jj.y = (e0 + 1 < e_end) ? ei[E+e0 + 1] : sent;
            jj.z = (e0 + 2 < e_end) ? ei[E+e0 + 2] : sent;
            jj.w = (e0 + 3 < e_end) ? ei[E+e0 + 3] : sent;
        }
        #pragma unroll
        for (int s = 0; s < 4; ++s) {
            const int iv = (s == 0) ? ii.x : (s == 1) ? ii.y : (s == 2) ? ii.z : ii.w;
            const int jv = (s == 0) ? jj.x : (s == 1) ? jj.y : (s == 2) ? jj.z : jj.w;
            const unsigned int ini = (unsigned int)(iv - lo) < CHUNK_NODES;
            const unsigned int inj = (unsigned int)(jv - lo) < CHUNK_NODES;
            const bool p = (ini | inj) != 0;
            const unsigned long long m = __ballot(p);
            if (p) {
                const unsigned int off = __popcll(m & ((1ull << lane) - 1ull));
                unsigned int qp = tail + off; if (qp >= QCAP) qp -= QCAP;
                q[w][qp] = (unsigned int)(e0 + s) | (ini << 30) | (inj << 31);
            }
            const unsigned int c = (unsigned int)__popcll(m);
            tail += c; if (tail >= QCAP) tail -= QCAP;
            cnt  += c;
        }
        while (cnt >= 64) drain(64);
    }
    while (cnt > 0) drain(cnt < 64 ? cnt : 64);

    __syncthreads();
    float* dst = partials + (size_t)(slice * chunks + chunk) * CHUNK_FLOATS;
    for (int idx = 4 * t; idx < CHUNK_FLOATS; idx += 4 * BLOCK)
        *(float4*)(dst + idx) = *(const float4*)&facc[idx];
    if (t < NUM_GRAPHS) atomicAdd(&energy[t], ebins[t]);
}

// Pass B: forces[f] = sum over slices of the chunk-partial holding f.
__global__ __launch_bounds__(256) void reduce_kernel(
    const float* __restrict__ partials,
    float*       __restrict__ forces,
    int total_floats, int chunks, int slices)
{
    const int f = blockIdx.x * 256 + threadIdx.x;
    if (f >= total_floats) return;
    const int chunk = f / CHUNK_FLOATS;
    const int rem   = f - chunk * CHUNK_FLOATS;
    float sum = 0.f;
    for (int s = 0; s < slices; ++s)
        sum += partials[(size_t)(s * chunks + chunk) * CHUNK_FLOATS + rem];
    forces[f] = sum;
}

extern "C" void kernel_launch(void* const* d_in, const int* in_sizes, int n_in,
                              void* d_out, int out_size, void* d_ws, size_t ws_size,
                              hipStream_t stream) {
    const float* pos   = (const float*)d_in[0];
    const int*   ei    = (const int*)d_in[1];
    const int*   batch = (const int*)d_in[2];

    const int E = in_sizes[1] / 2;     // edge_index is [2, E]
    const int N = in_sizes[0] / 3;     // pos is [N, 3]

    float* energy = (float*)d_out;            // first 64 floats
    float* forces = (float*)d_out + NUM_GRAPHS;

    const int chunks = (N + CHUNK_NODES - 1) / CHUNK_NODES;   // 10 for N=100000

    // slices: prefer SLICES (24, swizzle-friendly, grid = 240 <= 256 CUs);
    // fall back to whatever the workspace fits.
    const size_t slice_bytes = (size_t)chunks * CHUNK_FLOATS * sizeof(float);
    int slices = SLICES;
    int swizzle = 1;
    if ((size_t)slices * slice_bytes > ws_size) {
        slices = (int)(ws_size / slice_bytes);
        if (slices < 1) slices = 1;
        swizzle = 0;
    }
    // per_slice multiple of 4096 so scan int4 loads stay aligned & in-slice
    int per_slice = (E + slices - 1) / slices;
    per_slice = (per_slice + 4095) & ~4095;

    // Only energy accumulates via atomics into d_out; forces fully overwritten.
    hipMemsetAsync(d_out, 0, NUM_GRAPHS * sizeof(float), stream);

    edge_scan_kernel<<<chunks * slices, BLOCK, 0, stream>>>(
        pos, ei, batch, energy, (float*)d_ws, E, chunks, slices, per_slice, swizzle);

    const int total_floats = 3 * N;
    reduce_kernel<<<(total_floats + 255) / 256, 256, 0, stream>>>(
        (const float*)d_ws, forces, total_floats, chunks, slices);
}